// Round 14
// baseline (136.088 us; speedup 1.0000x reference)
//
#include <hip/hip_runtime.h>

#define NS 10000
#define DD 64
#define HH 128
#define EE 50000
#define SLOPE 0.01f

typedef __attribute__((ext_vector_type(8))) short short8;
typedef __attribute__((ext_vector_type(4))) float f32x4;

static __device__ __forceinline__ unsigned short f2bf(float f) {
  unsigned int u = __float_as_uint(f);
  u += 0x7fff + ((u >> 16) & 1);   // round-to-nearest-even
  return (unsigned short)(u >> 16);
}

__device__ __forceinline__ float wave_sum64(float v) {
  #pragma unroll
  for (int m = 32; m >= 1; m >>= 1) v += __shfl_xor(v, m, 64);
  return v;
}

// blocks [0,128): per-k 64x64 LDS transpose of w2 -> w2t2.
// blocks [128, 128+2500): LN(+bf16), degree counts, ea->bf16, w1t, b2t.
// NOTE: agg|cnt zeroing is a SEPARATE prior memset — zero-fill inside this
// kernel races with the atomic degree counting (r13 bug).
#define TBLK 128
__global__ __launch_bounds__(256) void k_prep(const float* __restrict__ x,
    const float* __restrict__ gamma, const float* __restrict__ beta,
    float* __restrict__ h, unsigned short* __restrict__ hbf,
    const float* __restrict__ ea, unsigned short* __restrict__ eabf,
    const float* __restrict__ w2, unsigned short* __restrict__ w2t2,
    const float* __restrict__ w1, unsigned short* __restrict__ w1t,
    const float* __restrict__ b2, unsigned short* __restrict__ b2t,
    const int* __restrict__ ei, int* __restrict__ cntsrc,
    int* __restrict__ cntdst) {
  __shared__ float tile[64][65];
  int t = threadIdx.x;
  int bid = blockIdx.x;
  if (bid < TBLK) {
    int k = bid;
    #pragma unroll
    for (int i = 0; i < 16; ++i) {
      int idx = t + i * 256;          // d*64+f
      tile[idx >> 6][idx & 63] = w2[k * (DD * DD) + idx];
    }
    __syncthreads();
    #pragma unroll
    for (int it = 0; it < 2; ++it) {
      int slot = t + it * 256;        // 0..511
      int f = slot >> 3, l8 = slot & 7;
      short8 o;
      #pragma unroll
      for (int j = 0; j < 8; ++j) o[j] = f2bf(tile[l8 * 8 + j][f]);
      *(short8*)(w2t2 + ((size_t)(f * HH + k)) * DD + l8 * 8) = o;
    }
    return;
  }
  int pbid = bid - TBLK;
  int gid = pbid * 256 + t;
  if (gid < EE) {
    atomicAdd(&cntsrc[ei[gid]], 1);
    atomicAdd(&cntdst[ei[EE + gid]], 1);
  }
  if (gid < EE * DD / 8) {
    const float4* sp = (const float4*)(ea + (size_t)gid * 8);
    float4 v0 = sp[0], v1 = sp[1];
    short8 o;
    o[0] = f2bf(v0.x); o[1] = f2bf(v0.y); o[2] = f2bf(v0.z); o[3] = f2bf(v0.w);
    o[4] = f2bf(v1.x); o[5] = f2bf(v1.y); o[6] = f2bf(v1.z); o[7] = f2bf(v1.w);
    *(short8*)(eabf + (size_t)gid * 8) = o;
  }
  if (gid < DD * HH) {   // w1t[hc*64+d] = w1[d*128+hc]
    int d = gid & 63, hc = gid >> 6;
    w1t[gid] = f2bf(w1[d * HH + hc]);
  }
  if (gid < DD * DD) {   // b2t[f*64+d] = b2[d*64+f]
    int d = gid & 63, f = gid >> 6;
    b2t[gid] = f2bf(b2[d * DD + f]);
  }
  int wid = t >> 6;
  int lane = t & 63;
  int row = pbid * 4 + wid;
  if (row >= NS) return;
  float v = x[row * DD + lane];
  float s = wave_sum64(v);
  float s2 = wave_sum64(v * v);
  float mu = s * (1.0f / 64.0f);
  float var = s2 * (1.0f / 64.0f) - mu * mu;
  float r = rsqrtf(var + 1e-5f);
  float hn = (v - mu) * r * gamma[lane] + beta[lane];
  float hv = hn >= 0.f ? hn : SLOPE * hn;
  h[row * DD + lane] = hv;
  hbf[row * DD + lane] = f2bf(hv);
}

// blocks [0,UBLK): ubf = bf16(leaky(eabf@w1+b1)) (staging-free MFMA);
// blocks [UBLK,UBLK+CBLK): cc = h@b2; block UBLK+CBLK: scan -> rowptr,cursor.
#define UBLK 782
#define CBLK 157
__global__ __launch_bounds__(256) void k_mid(
    const unsigned short* __restrict__ eabf, const unsigned short* __restrict__ w1t,
    const float* __restrict__ b1, unsigned short* __restrict__ ubf,
    const unsigned short* __restrict__ hbf, const unsigned short* __restrict__ b2t,
    float* __restrict__ cc, const int* __restrict__ cntsrc,
    int* __restrict__ rowptr, int* __restrict__ cursor) {
  int t = threadIdx.x;
  int bid = blockIdx.x;
  int w = t >> 6, lane = t & 63, lr = lane & 15, lg = lane >> 4;
  if (bid < UBLK) {
    int r0 = bid * 64 + w * 16;
    int ra = r0 + lr; if (ra >= EE) ra = EE - 1;
    short8 a0 = *(const short8*)(eabf + (size_t)ra * DD + lg * 8);
    short8 a1 = *(const short8*)(eabf + (size_t)ra * DD + 32 + lg * 8);
    short8 bb0[8], bb1[8];
    #pragma unroll
    for (int ni = 0; ni < 8; ++ni) {
      const unsigned short* bp = w1t + (ni * 16 + lr) * DD;
      bb0[ni] = *(const short8*)(bp + lg * 8);
      bb1[ni] = *(const short8*)(bp + 32 + lg * 8);
    }
    f32x4 acc[8] = {};
    #pragma unroll
    for (int ni = 0; ni < 8; ++ni) {
      acc[ni] = __builtin_amdgcn_mfma_f32_16x16x32_bf16(a0, bb0[ni], acc[ni], 0, 0, 0);
      acc[ni] = __builtin_amdgcn_mfma_f32_16x16x32_bf16(a1, bb1[ni], acc[ni], 0, 0, 0);
    }
    #pragma unroll
    for (int ni = 0; ni < 8; ++ni) {
      int col = ni * 16 + lr;
      float bb = b1[col];
      #pragma unroll
      for (int reg = 0; reg < 4; ++reg) {
        int gr = r0 + lg * 4 + reg;
        if (gr < EE) {
          float vv = acc[ni][reg] + bb;
          ubf[(size_t)gr * HH + col] = f2bf(vv >= 0.f ? vv : SLOPE * vv);
        }
      }
    }
  } else if (bid < UBLK + CBLK) {
    int row0 = (bid - UBLK) * 64;
    short8 a[4][2];
    #pragma unroll
    for (int mi = 0; mi < 4; ++mi) {
      int ra = row0 + mi * 16 + lr; if (ra >= NS) ra = NS - 1;
      a[mi][0] = *(const short8*)(hbf + (size_t)ra * DD + lg * 8);
      a[mi][1] = *(const short8*)(hbf + (size_t)ra * DD + 32 + lg * 8);
    }
    const unsigned short* bp = b2t + (w * 16 + lr) * DD;
    short8 b0 = *(const short8*)(bp + lg * 8);
    short8 b1v = *(const short8*)(bp + 32 + lg * 8);
    f32x4 acc[4] = {};
    #pragma unroll
    for (int mi = 0; mi < 4; ++mi) {
      acc[mi] = __builtin_amdgcn_mfma_f32_16x16x32_bf16(a[mi][0], b0, acc[mi], 0, 0, 0);
      acc[mi] = __builtin_amdgcn_mfma_f32_16x16x32_bf16(a[mi][1], b1v, acc[mi], 0, 0, 0);
    }
    #pragma unroll
    for (int mi = 0; mi < 4; ++mi)
      #pragma unroll
      for (int reg = 0; reg < 4; ++reg) {
        int gr = row0 + mi * 16 + lg * 4 + reg;
        if (gr < NS) cc[(size_t)gr * DD + w * 16 + lr] = acc[mi][reg];
      }
  } else {
    __shared__ int ps[256];
    const int CH = (NS + 255) / 256;   // 40
    int base = t * CH;
    int sum = 0;
    for (int i = 0; i < CH; ++i) {
      int idx = base + i;
      if (idx < NS) sum += cntsrc[idx];
    }
    ps[t] = sum;
    __syncthreads();
    for (int off = 1; off < 256; off <<= 1) {
      int v = (t >= off) ? ps[t - off] : 0;
      __syncthreads();
      ps[t] += v;
      __syncthreads();
    }
    int run = ps[t] - sum;
    for (int i = 0; i < CH; ++i) {
      int idx = base + i;
      if (idx < NS) {
        rowptr[idx] = run;
        cursor[idx] = run;
        run += cntsrc[idx];
      }
    }
    if (t == 255) rowptr[NS] = run;
  }
}

// T GEMM: 64 nodes x 128 c2-cols per block (27.6 KB LDS -> 5 blocks/CU).
// Staged loads up front, MFMA from LDS, store via LDS transpose (stride 132).
// Folds edge scatter (first chunk only). Grid x padded to 8 for XCD pinning.
__global__ __launch_bounds__(256) void k_T_mfma(
    const unsigned short* __restrict__ hbf, const unsigned short* __restrict__ w2t2,
    unsigned short* __restrict__ T, int n0, int n1, int gx,
    const int* __restrict__ ei, int* __restrict__ cursor,
    int* __restrict__ eord, int doScatter) {
  __shared__ unsigned short As[64][72];     // 9216 B
  __shared__ unsigned short Bs[128 * 72];   // 18432 B; reused as Ts[64][132]
  int t = threadIdx.x;
  if (doScatter) {
    int gid = (blockIdx.y * gx + blockIdx.x) * 256 + t;
    if (gid < EE) {
      int s = ei[gid];
      int pos = atomicAdd(&cursor[s], 1);
      eord[pos] = gid;
    }
  }
  int row0 = n0 + blockIdx.x * 64;
  if (row0 >= n1) return;
  int col0 = blockIdx.y * 128;
  #pragma unroll
  for (int i = 0; i < 2; ++i) {
    int idx = t + i * 256;
    int r = idx >> 3, cc = (idx & 7) * 8;
    int gr = row0 + r;
    short8 v = {};
    if (gr < n1) v = *(const short8*)(hbf + (size_t)gr * DD + cc);
    *(short8*)(&As[r][cc]) = v;
  }
  #pragma unroll
  for (int i = 0; i < 4; ++i) {
    int idx = t + i * 256;            // 0..1023
    int cL = idx >> 3, rr = (idx & 7) * 8;
    int gc = col0 + cL;
    short8 v = *(const short8*)(w2t2 + (size_t)gc * DD + rr);
    *(short8*)(&Bs[cL * 72 + rr]) = v;
  }
  __syncthreads();
  int w = t >> 6, lane = t & 63;
  int lr = lane & 15, lg = lane >> 4;
  f32x4 acc[4][2] = {};
  #pragma unroll
  for (int kk = 0; kk < 64; kk += 32) {
    short8 a[4], b[2];
    #pragma unroll
    for (int mi = 0; mi < 4; ++mi)
      a[mi] = *(const short8*)(&As[mi * 16 + lr][kk + lg * 8]);
    #pragma unroll
    for (int ni = 0; ni < 2; ++ni)
      b[ni] = *(const short8*)(&Bs[(w * 32 + ni * 16 + lr) * 72 + kk + lg * 8]);
    #pragma unroll
    for (int mi = 0; mi < 4; ++mi)
      #pragma unroll
      for (int ni = 0; ni < 2; ++ni)
        acc[mi][ni] = __builtin_amdgcn_mfma_f32_16x16x32_bf16(
            a[mi], b[ni], acc[mi][ni], 0, 0, 0);
  }
  __syncthreads();   // all waves done reading Bs
  #pragma unroll
  for (int mi = 0; mi < 4; ++mi)
    #pragma unroll
    for (int ni = 0; ni < 2; ++ni) {
      int col = w * 32 + ni * 16 + lr;
      #pragma unroll
      for (int reg = 0; reg < 4; ++reg)
        Bs[(mi * 16 + lg * 4 + reg) * 132 + col] = f2bf(acc[mi][ni][reg]);
    }
  __syncthreads();
  #pragma unroll
  for (int i = 0; i < 4; ++i) {
    int idx = t + i * 256;           // 0..1023
    int row = idx >> 4, seg = idx & 15;
    int gr = row0 + row;
    if (gr < n1) {
      short8 v = *(const short8*)(&Bs[row * 132 + seg * 8]);
      *(short8*)(T + (size_t)(gr - n0) * (HH * DD) + col0 + seg * 8) = v;
    }
  }
}

// Wave-per-node message pass; grid (gx,16) so chunk bx's consumers share
// the producer's XCD.
__global__ __launch_bounds__(256) void k_msg_wave(
    const unsigned short* __restrict__ ubf, const unsigned short* __restrict__ T,
    const float* __restrict__ cc, const int* __restrict__ ei,
    const int* __restrict__ rowptr, const int* __restrict__ eord,
    float* __restrict__ agg, int n0, int n1) {
  int wid = threadIdx.x >> 6;
  int lane = threadIdx.x & 63;
  int s = n0 + blockIdx.x * 64 + blockIdx.y * 4 + wid;
  if (s >= n1) return;
  int beg = rowptr[s];
  int deg = rowptr[s + 1] - beg;
  if (deg == 0) return;
  int lr = lane & 15, lg = lane >> 4;
  int ev = 0, dv = 0;
  if (lane < 16 && lane < deg) {
    ev = eord[beg + lane];
    dv = ei[EE + ev];
  }
  const unsigned short* tp = T + (size_t)(s - n0) * (HH * DD);
  short8 b[4][4];
  #pragma unroll
  for (int ft = 0; ft < 4; ++ft)
    #pragma unroll
    for (int kk = 0; kk < 4; ++kk)
      b[ft][kk] =
          *(const short8*)(tp + (ft * 16 + lr) * HH + kk * 32 + lg * 8);
  float clv[4];
  #pragma unroll
  for (int ft = 0; ft < 4; ++ft) clv[ft] = cc[(size_t)s * DD + ft * 16 + lr];

  for (int p0 = 0; p0 < deg; p0 += 16) {
    if (p0) {
      ev = 0; dv = 0;
      if (lane < 16 && p0 + lane < deg) {
        ev = eord[beg + p0 + lane];
        dv = ei[EE + ev];
      }
    }
    int el = __shfl(ev, (p0 + lr < deg) ? lr : 0);
    const unsigned short* up = ubf + (size_t)el * HH;
    short8 au[4];
    #pragma unroll
    for (int kk = 0; kk < 4; ++kk)
      au[kk] = *(const short8*)(up + kk * 32 + lg * 8);
    f32x4 acc[4] = {};
    #pragma unroll
    for (int kk = 0; kk < 4; ++kk)
      #pragma unroll
      for (int ft = 0; ft < 4; ++ft)
        acc[ft] = __builtin_amdgcn_mfma_f32_16x16x32_bf16(au[kk], b[ft][kk],
                                                          acc[ft], 0, 0, 0);
    #pragma unroll
    for (int reg = 0; reg < 4; ++reg) {
      int eidx = p0 + lg * 4 + reg;
      int dstn = __shfl(dv, lg * 4 + reg);
      if (eidx < deg) {
        #pragma unroll
        for (int ft = 0; ft < 4; ++ft)
          atomicAdd(&agg[(size_t)dstn * DD + ft * 16 + lr],
                    acc[ft][reg] + clv[ft]);
      }
    }
  }
}

// out = x + agg/max(cnt,1) + h@root + bias
__global__ __launch_bounds__(256) void k_final(const float* __restrict__ x,
    const float* __restrict__ h, const float* __restrict__ root,
    const float* __restrict__ bias, const float* __restrict__ agg,
    const int* __restrict__ cnt, float* __restrict__ out) {
  __shared__ float Bs[DD][DD + 1];
  __shared__ float As[32][DD];
  int t = threadIdx.x;
  #pragma unroll
  for (int i = 0; i < 16; ++i) {
    int idx = t + i * 256;
    Bs[idx >> 6][idx & 63] = root[idx];
  }
  int row0 = blockIdx.x * 32;
  #pragma unroll
  for (int i = 0; i < 8; ++i) {
    int idx = t + i * 256;
    int r = idx >> 6, d = idx & 63;
    int gr = row0 + r;
    As[r][d] = (gr < NS) ? h[gr * DD + d] : 0.f;
  }
  __syncthreads();
  int r = t >> 3;
  int c0 = (t & 7) * 8;
  int gr = row0 + r;
  if (gr >= NS) return;
  float acc[8] = {};
  for (int d = 0; d < DD; ++d) {
    float a = As[r][d];
    #pragma unroll
    for (int j = 0; j < 8; ++j) acc[j] += a * Bs[d][c0 + j];
  }
  float inv = 1.0f / fmaxf((float)cnt[gr], 1.0f);
  #pragma unroll
  for (int j = 0; j < 8; ++j) {
    size_t gi = (size_t)gr * DD + c0 + j;
    out[gi] = x[gi] + agg[gi] * inv + acc[j] + bias[c0 + j];
  }
}

extern "C" void kernel_launch(void* const* d_in, const int* in_sizes, int n_in,
                              void* d_out, int out_size, void* d_ws, size_t ws_size,
                              hipStream_t stream) {
  const float* x     = (const float*)d_in[0];
  const float* ea    = (const float*)d_in[1];
  const float* gamma = (const float*)d_in[2];
  const float* beta  = (const float*)d_in[3];
  const float* w1    = (const float*)d_in[4];
  const float* b1    = (const float*)d_in[5];
  const float* w2    = (const float*)d_in[6];
  const float* b2    = (const float*)d_in[7];
  const float* root  = (const float*)d_in[8];
  const float* bias  = (const float*)d_in[9];
  const int*   ei    = (const int*)d_in[10];
  float* out = (float*)d_out;

  char* p = (char*)d_ws;
  auto carve = [&](size_t bytes) {
    char* q = p;
    p += (bytes + 255) & ~(size_t)255;
    return q;
  };
  float* h             = (float*)carve(sizeof(float) * NS * DD);
  unsigned short* hbf  = (unsigned short*)carve(sizeof(short) * NS * DD);
  float* cc            = (float*)carve(sizeof(float) * NS * DD);
  unsigned short* w2t2 = (unsigned short*)carve(sizeof(short) * HH * DD * DD);
  unsigned short* w1t  = (unsigned short*)carve(sizeof(short) * DD * HH);
  unsigned short* b2t  = (unsigned short*)carve(sizeof(short) * DD * DD);
  unsigned short* eabf = (unsigned short*)carve(sizeof(short) * (size_t)EE * DD);
  unsigned short* ubf  = (unsigned short*)carve(sizeof(short) * (size_t)EE * HH);
  int* rowptr          = (int*)carve(sizeof(int) * (NS + 1));
  int* cursor          = (int*)carve(sizeof(int) * NS);
  int* eord            = (int*)carve(sizeof(int) * EE);
  // contiguous zero-region: agg | cntdst | cntsrc (memset BEFORE k_prep —
  // zeroing inside k_prep races with its atomic counting; r13 lesson)
  char* z0 = p;
  float* agg           = (float*)carve(sizeof(float) * NS * DD);
  int* cntdst          = (int*)carve(sizeof(int) * NS);
  int* cntsrc          = (int*)carve(sizeof(int) * NS);
  size_t zlen = (size_t)(p - z0);
  size_t fixed = (size_t)(p - (char*)d_ws);

  size_t freeb = (ws_size > fixed) ? (ws_size - fixed - 256) : 0;
  int rows = (int)(freeb / (sizeof(short) * HH * DD));
  if (rows >= NS) rows = NS;       // single chunk when it fits (ws = 256 MiB)
  else { rows &= ~63; if (rows < 64) rows = 64; }
  unsigned short* Tt = (unsigned short*)carve(sizeof(short) * (size_t)rows * HH * DD);

  hipMemsetAsync(z0, 0, zlen, stream);
  k_prep<<<dim3(TBLK + (NS + 3) / 4), dim3(256), 0, stream>>>(
      x, gamma, beta, h, hbf, ea, eabf, w2, w2t2, w1, w1t, b2, b2t,
      ei, cntsrc, cntdst);
  k_mid<<<dim3(UBLK + CBLK + 1), dim3(256), 0, stream>>>(
      eabf, w1t, b1, ubf, hbf, b2t, cc, cntsrc, rowptr, cursor);

  for (int n0 = 0; n0 < NS; n0 += rows) {
    int n1 = n0 + rows;
    if (n1 > NS) n1 = NS;
    int nr = n1 - n0;
    int gx = (((nr + 63) / 64) + 7) & ~7;   // pad to mult of 8 for XCD pinning
    k_T_mfma<<<dim3(gx, (HH * DD) / 128), dim3(256), 0, stream>>>(
        hbf, w2t2, Tt, n0, n1, gx, ei, cursor, eord, n0 == 0 ? 1 : 0);
    k_msg_wave<<<dim3(gx, 16), dim3(256), 0, stream>>>(
        ubf, Tt, cc, ei, rowptr, eord, agg, n0, n1);
  }

  k_final<<<dim3((NS + 31) / 32), dim3(256), 0, stream>>>(x, h, root, bias, agg,
                                                          cntdst, out);
}

// Round 15
// 119.481 us; speedup vs baseline: 1.1390x; 1.1390x over previous
//
#include <hip/hip_runtime.h>

#define NS 10000
#define DD 64
#define HH 128
#define EE 50000
#define SLOPE 0.01f

typedef __attribute__((ext_vector_type(8))) short short8;
typedef __attribute__((ext_vector_type(4))) float f32x4;

static __device__ __forceinline__ unsigned short f2bf(float f) {
  unsigned int u = __float_as_uint(f);
  u += 0x7fff + ((u >> 16) & 1);   // round-to-nearest-even
  return (unsigned short)(u >> 16);
}

__device__ __forceinline__ float wave_sum64(float v) {
  #pragma unroll
  for (int m = 32; m >= 1; m >>= 1) v += __shfl_xor(v, m, 64);
  return v;
}

// blocks [0,128): per-k 64x64 LDS transpose of w2 -> w2t2.
// blocks [128, 128+2500): LN(+bf16), degree counts, ea->bf16, w1t, b2t.
// agg|cnt zeroing stays a SEPARATE prior memset (r13 race lesson).
#define TBLK 128
__global__ __launch_bounds__(256) void k_prep(const float* __restrict__ x,
    const float* __restrict__ gamma, const float* __restrict__ beta,
    float* __restrict__ h, unsigned short* __restrict__ hbf,
    const float* __restrict__ ea, unsigned short* __restrict__ eabf,
    const float* __restrict__ w2, unsigned short* __restrict__ w2t2,
    const float* __restrict__ w1, unsigned short* __restrict__ w1t,
    const float* __restrict__ b2, unsigned short* __restrict__ b2t,
    const int* __restrict__ ei, int* __restrict__ cntsrc,
    int* __restrict__ cntdst) {
  __shared__ float tile[64][65];
  int t = threadIdx.x;
  int bid = blockIdx.x;
  if (bid < TBLK) {
    int k = bid;
    #pragma unroll
    for (int i = 0; i < 16; ++i) {
      int idx = t + i * 256;          // d*64+f
      tile[idx >> 6][idx & 63] = w2[k * (DD * DD) + idx];
    }
    __syncthreads();
    #pragma unroll
    for (int it = 0; it < 2; ++it) {
      int slot = t + it * 256;        // 0..511
      int f = slot >> 3, l8 = slot & 7;
      short8 o;
      #pragma unroll
      for (int j = 0; j < 8; ++j) o[j] = f2bf(tile[l8 * 8 + j][f]);
      *(short8*)(w2t2 + ((size_t)(f * HH + k)) * DD + l8 * 8) = o;
    }
    return;
  }
  int pbid = bid - TBLK;
  int gid = pbid * 256 + t;
  if (gid < EE) {
    atomicAdd(&cntsrc[ei[gid]], 1);
    atomicAdd(&cntdst[ei[EE + gid]], 1);
  }
  if (gid < EE * DD / 8) {
    const float4* sp = (const float4*)(ea + (size_t)gid * 8);
    float4 v0 = sp[0], v1 = sp[1];
    short8 o;
    o[0] = f2bf(v0.x); o[1] = f2bf(v0.y); o[2] = f2bf(v0.z); o[3] = f2bf(v0.w);
    o[4] = f2bf(v1.x); o[5] = f2bf(v1.y); o[6] = f2bf(v1.z); o[7] = f2bf(v1.w);
    *(short8*)(eabf + (size_t)gid * 8) = o;
  }
  if (gid < DD * HH) {   // w1t[hc*64+d] = w1[d*128+hc]
    int d = gid & 63, hc = gid >> 6;
    w1t[gid] = f2bf(w1[d * HH + hc]);
  }
  if (gid < DD * DD) {   // b2t[f*64+d] = b2[d*64+f]
    int d = gid & 63, f = gid >> 6;
    b2t[gid] = f2bf(b2[d * DD + f]);
  }
  int wid = t >> 6;
  int lane = t & 63;
  int row = pbid * 4 + wid;
  if (row >= NS) return;
  float v = x[row * DD + lane];
  float s = wave_sum64(v);
  float s2 = wave_sum64(v * v);
  float mu = s * (1.0f / 64.0f);
  float var = s2 * (1.0f / 64.0f) - mu * mu;
  float r = rsqrtf(var + 1e-5f);
  float hn = (v - mu) * r * gamma[lane] + beta[lane];
  float hv = hn >= 0.f ? hn : SLOPE * hn;
  h[row * DD + lane] = hv;
  hbf[row * DD + lane] = f2bf(hv);
}

// Merged mid+T: blocks [0,UBLK): ubf = bf16(leaky(eabf@w1+b1));
// [UBLK,UBLK+CBLK): cc = h@b2; [UBLK+CBLK]: scan -> rowptr,cursor;
// [TSTART, TSTART+gx*64): T GEMM 64 nodes x 128 c2-cols (27.6KB LDS).
// mid blocks (store-light MFMA) overlap T blocks' store-drain phases.
// TSTART multiple of 8 preserves XCD pinning: T-chunk bx -> XCD bx%8.
#define UBLK 782
#define CBLK 157
#define TSTART 944
__global__ __launch_bounds__(256) void k_midT(
    const unsigned short* __restrict__ eabf, const unsigned short* __restrict__ w1t,
    const float* __restrict__ b1, unsigned short* __restrict__ ubf,
    const unsigned short* __restrict__ hbf, const unsigned short* __restrict__ b2t,
    float* __restrict__ cc, const int* __restrict__ cntsrc,
    int* __restrict__ rowptr, int* __restrict__ cursor,
    const unsigned short* __restrict__ w2t2, unsigned short* __restrict__ T,
    int n0, int n1, int gx, int doMid) {
  __shared__ unsigned short As[64][72];     // 9216 B
  __shared__ unsigned short Bs[128 * 72];   // 18432 B; reused as Ts[64][132]
  int t = threadIdx.x;
  int bid = blockIdx.x;
  int w = t >> 6, lane = t & 63, lr = lane & 15, lg = lane >> 4;
  if (bid < UBLK) {
    if (!doMid) return;
    int r0 = bid * 64 + w * 16;
    int ra = r0 + lr; if (ra >= EE) ra = EE - 1;
    short8 a0 = *(const short8*)(eabf + (size_t)ra * DD + lg * 8);
    short8 a1 = *(const short8*)(eabf + (size_t)ra * DD + 32 + lg * 8);
    short8 bb0[8], bb1[8];
    #pragma unroll
    for (int ni = 0; ni < 8; ++ni) {
      const unsigned short* bp = w1t + (ni * 16 + lr) * DD;
      bb0[ni] = *(const short8*)(bp + lg * 8);
      bb1[ni] = *(const short8*)(bp + 32 + lg * 8);
    }
    f32x4 acc[8] = {};
    #pragma unroll
    for (int ni = 0; ni < 8; ++ni) {
      acc[ni] = __builtin_amdgcn_mfma_f32_16x16x32_bf16(a0, bb0[ni], acc[ni], 0, 0, 0);
      acc[ni] = __builtin_amdgcn_mfma_f32_16x16x32_bf16(a1, bb1[ni], acc[ni], 0, 0, 0);
    }
    #pragma unroll
    for (int ni = 0; ni < 8; ++ni) {
      int col = ni * 16 + lr;
      float bb = b1[col];
      #pragma unroll
      for (int reg = 0; reg < 4; ++reg) {
        int gr = r0 + lg * 4 + reg;
        if (gr < EE) {
          float vv = acc[ni][reg] + bb;
          ubf[(size_t)gr * HH + col] = f2bf(vv >= 0.f ? vv : SLOPE * vv);
        }
      }
    }
    return;
  } else if (bid < UBLK + CBLK) {
    if (!doMid) return;
    int row0 = (bid - UBLK) * 64;
    short8 a[4][2];
    #pragma unroll
    for (int mi = 0; mi < 4; ++mi) {
      int ra = row0 + mi * 16 + lr; if (ra >= NS) ra = NS - 1;
      a[mi][0] = *(const short8*)(hbf + (size_t)ra * DD + lg * 8);
      a[mi][1] = *(const short8*)(hbf + (size_t)ra * DD + 32 + lg * 8);
    }
    const unsigned short* bp = b2t + (w * 16 + lr) * DD;
    short8 b0 = *(const short8*)(bp + lg * 8);
    short8 b1v = *(const short8*)(bp + 32 + lg * 8);
    f32x4 acc[4] = {};
    #pragma unroll
    for (int mi = 0; mi < 4; ++mi) {
      acc[mi] = __builtin_amdgcn_mfma_f32_16x16x32_bf16(a[mi][0], b0, acc[mi], 0, 0, 0);
      acc[mi] = __builtin_amdgcn_mfma_f32_16x16x32_bf16(a[mi][1], b1v, acc[mi], 0, 0, 0);
    }
    #pragma unroll
    for (int mi = 0; mi < 4; ++mi)
      #pragma unroll
      for (int reg = 0; reg < 4; ++reg) {
        int gr = row0 + mi * 16 + lg * 4 + reg;
        if (gr < NS) cc[(size_t)gr * DD + w * 16 + lr] = acc[mi][reg];
      }
    return;
  } else if (bid == UBLK + CBLK) {
    if (!doMid) return;
    int* ps = (int*)&As[0][0];
    const int CH = (NS + 255) / 256;   // 40
    int base = t * CH;
    int sum = 0;
    for (int i = 0; i < CH; ++i) {
      int idx = base + i;
      if (idx < NS) sum += cntsrc[idx];
    }
    ps[t] = sum;
    __syncthreads();
    for (int off = 1; off < 256; off <<= 1) {
      int v = (t >= off) ? ps[t - off] : 0;
      __syncthreads();
      ps[t] += v;
      __syncthreads();
    }
    int run = ps[t] - sum;
    for (int i = 0; i < CH; ++i) {
      int idx = base + i;
      if (idx < NS) {
        rowptr[idx] = run;
        cursor[idx] = run;
        run += cntsrc[idx];
      }
    }
    if (t == 255) rowptr[NS] = run;
    return;
  }
  if (bid < TSTART) return;          // pad blocks
  int tb = bid - TSTART;
  int bx = tb % gx, by = tb / gx;    // XCD: (TSTART+by*gx+bx)%8 == bx%8 (gx%8==0)
  int row0 = n0 + bx * 64;
  if (row0 >= n1) return;
  int col0 = by * 128;
  #pragma unroll
  for (int i = 0; i < 2; ++i) {
    int idx = t + i * 256;
    int r = idx >> 3, cc2 = (idx & 7) * 8;
    int gr = row0 + r;
    short8 v = {};
    if (gr < n1) v = *(const short8*)(hbf + (size_t)gr * DD + cc2);
    *(short8*)(&As[r][cc2]) = v;
  }
  #pragma unroll
  for (int i = 0; i < 4; ++i) {
    int idx = t + i * 256;            // 0..1023
    int cL = idx >> 3, rr = (idx & 7) * 8;
    int gc = col0 + cL;
    short8 v = *(const short8*)(w2t2 + (size_t)gc * DD + rr);
    *(short8*)(&Bs[cL * 72 + rr]) = v;
  }
  __syncthreads();
  f32x4 acc[4][2] = {};
  #pragma unroll
  for (int kk = 0; kk < 64; kk += 32) {
    short8 a[4], b[2];
    #pragma unroll
    for (int mi = 0; mi < 4; ++mi)
      a[mi] = *(const short8*)(&As[mi * 16 + lr][kk + lg * 8]);
    #pragma unroll
    for (int ni = 0; ni < 2; ++ni)
      b[ni] = *(const short8*)(&Bs[(w * 32 + ni * 16 + lr) * 72 + kk + lg * 8]);
    #pragma unroll
    for (int mi = 0; mi < 4; ++mi)
      #pragma unroll
      for (int ni = 0; ni < 2; ++ni)
        acc[mi][ni] = __builtin_amdgcn_mfma_f32_16x16x32_bf16(
            a[mi], b[ni], acc[mi][ni], 0, 0, 0);
  }
  __syncthreads();   // all waves done reading Bs
  #pragma unroll
  for (int mi = 0; mi < 4; ++mi)
    #pragma unroll
    for (int ni = 0; ni < 2; ++ni) {
      int col = w * 32 + ni * 16 + lr;
      #pragma unroll
      for (int reg = 0; reg < 4; ++reg)
        Bs[(mi * 16 + lg * 4 + reg) * 132 + col] = f2bf(acc[mi][ni][reg]);
    }
  __syncthreads();
  #pragma unroll
  for (int i = 0; i < 4; ++i) {
    int idx = t + i * 256;           // 0..1023
    int row = idx >> 4, seg = idx & 15;
    int gr = row0 + row;
    if (gr < n1) {
      short8 v = *(const short8*)(&Bs[row * 132 + seg * 8]);
      *(short8*)(T + (size_t)(gr - n0) * (HH * DD) + col0 + seg * 8) = v;
    }
  }
}

__global__ __launch_bounds__(256) void k_scatter(const int* __restrict__ ei,
    int* __restrict__ cursor, int* __restrict__ eord) {
  int e = blockIdx.x * 256 + threadIdx.x;
  if (e < EE) {
    int s = ei[e];
    int pos = atomicAdd(&cursor[s], 1);
    eord[pos] = e;
  }
}

// Wave-per-node message pass; grid (gx,16) so chunk bx's consumers share
// the producer's XCD.
__global__ __launch_bounds__(256) void k_msg_wave(
    const unsigned short* __restrict__ ubf, const unsigned short* __restrict__ T,
    const float* __restrict__ cc, const int* __restrict__ ei,
    const int* __restrict__ rowptr, const int* __restrict__ eord,
    float* __restrict__ agg, int n0, int n1) {
  int wid = threadIdx.x >> 6;
  int lane = threadIdx.x & 63;
  int s = n0 + blockIdx.x * 64 + blockIdx.y * 4 + wid;
  if (s >= n1) return;
  int beg = rowptr[s];
  int deg = rowptr[s + 1] - beg;
  if (deg == 0) return;
  int lr = lane & 15, lg = lane >> 4;
  int ev = 0, dv = 0;
  if (lane < 16 && lane < deg) {
    ev = eord[beg + lane];
    dv = ei[EE + ev];
  }
  const unsigned short* tp = T + (size_t)(s - n0) * (HH * DD);
  short8 b[4][4];
  #pragma unroll
  for (int ft = 0; ft < 4; ++ft)
    #pragma unroll
    for (int kk = 0; kk < 4; ++kk)
      b[ft][kk] =
          *(const short8*)(tp + (ft * 16 + lr) * HH + kk * 32 + lg * 8);
  float clv[4];
  #pragma unroll
  for (int ft = 0; ft < 4; ++ft) clv[ft] = cc[(size_t)s * DD + ft * 16 + lr];

  for (int p0 = 0; p0 < deg; p0 += 16) {
    if (p0) {
      ev = 0; dv = 0;
      if (lane < 16 && p0 + lane < deg) {
        ev = eord[beg + p0 + lane];
        dv = ei[EE + ev];
      }
    }
    int el = __shfl(ev, (p0 + lr < deg) ? lr : 0);
    const unsigned short* up = ubf + (size_t)el * HH;
    short8 au[4];
    #pragma unroll
    for (int kk = 0; kk < 4; ++kk)
      au[kk] = *(const short8*)(up + kk * 32 + lg * 8);
    f32x4 acc[4] = {};
    #pragma unroll
    for (int kk = 0; kk < 4; ++kk)
      #pragma unroll
      for (int ft = 0; ft < 4; ++ft)
        acc[ft] = __builtin_amdgcn_mfma_f32_16x16x32_bf16(au[kk], b[ft][kk],
                                                          acc[ft], 0, 0, 0);
    #pragma unroll
    for (int reg = 0; reg < 4; ++reg) {
      int eidx = p0 + lg * 4 + reg;
      int dstn = __shfl(dv, lg * 4 + reg);
      if (eidx < deg) {
        #pragma unroll
        for (int ft = 0; ft < 4; ++ft)
          atomicAdd(&agg[(size_t)dstn * DD + ft * 16 + lr],
                    acc[ft][reg] + clv[ft]);
      }
    }
  }
}

// out = x + agg/max(cnt,1) + h@root + bias
__global__ __launch_bounds__(256) void k_final(const float* __restrict__ x,
    const float* __restrict__ h, const float* __restrict__ root,
    const float* __restrict__ bias, const float* __restrict__ agg,
    const int* __restrict__ cnt, float* __restrict__ out) {
  __shared__ float Bs[DD][DD + 1];
  __shared__ float As[32][DD];
  int t = threadIdx.x;
  #pragma unroll
  for (int i = 0; i < 16; ++i) {
    int idx = t + i * 256;
    Bs[idx >> 6][idx & 63] = root[idx];
  }
  int row0 = blockIdx.x * 32;
  #pragma unroll
  for (int i = 0; i < 8; ++i) {
    int idx = t + i * 256;
    int r = idx >> 6, d = idx & 63;
    int gr = row0 + r;
    As[r][d] = (gr < NS) ? h[gr * DD + d] : 0.f;
  }
  __syncthreads();
  int r = t >> 3;
  int c0 = (t & 7) * 8;
  int gr = row0 + r;
  if (gr >= NS) return;
  float acc[8] = {};
  for (int d = 0; d < DD; ++d) {
    float a = As[r][d];
    #pragma unroll
    for (int j = 0; j < 8; ++j) acc[j] += a * Bs[d][c0 + j];
  }
  float inv = 1.0f / fmaxf((float)cnt[gr], 1.0f);
  #pragma unroll
  for (int j = 0; j < 8; ++j) {
    size_t gi = (size_t)gr * DD + c0 + j;
    out[gi] = x[gi] + agg[gi] * inv + acc[j] + bias[c0 + j];
  }
}

extern "C" void kernel_launch(void* const* d_in, const int* in_sizes, int n_in,
                              void* d_out, int out_size, void* d_ws, size_t ws_size,
                              hipStream_t stream) {
  const float* x     = (const float*)d_in[0];
  const float* ea    = (const float*)d_in[1];
  const float* gamma = (const float*)d_in[2];
  const float* beta  = (const float*)d_in[3];
  const float* w1    = (const float*)d_in[4];
  const float* b1    = (const float*)d_in[5];
  const float* w2    = (const float*)d_in[6];
  const float* b2    = (const float*)d_in[7];
  const float* root  = (const float*)d_in[8];
  const float* bias  = (const float*)d_in[9];
  const int*   ei    = (const int*)d_in[10];
  float* out = (float*)d_out;

  char* p = (char*)d_ws;
  auto carve = [&](size_t bytes) {
    char* q = p;
    p += (bytes + 255) & ~(size_t)255;
    return q;
  };
  float* h             = (float*)carve(sizeof(float) * NS * DD);
  unsigned short* hbf  = (unsigned short*)carve(sizeof(short) * NS * DD);
  float* cc            = (float*)carve(sizeof(float) * NS * DD);
  unsigned short* w2t2 = (unsigned short*)carve(sizeof(short) * HH * DD * DD);
  unsigned short* w1t  = (unsigned short*)carve(sizeof(short) * DD * HH);
  unsigned short* b2t  = (unsigned short*)carve(sizeof(short) * DD * DD);
  unsigned short* eabf = (unsigned short*)carve(sizeof(short) * (size_t)EE * DD);
  unsigned short* ubf  = (unsigned short*)carve(sizeof(short) * (size_t)EE * HH);
  int* rowptr          = (int*)carve(sizeof(int) * (NS + 1));
  int* cursor          = (int*)carve(sizeof(int) * NS);
  int* eord            = (int*)carve(sizeof(int) * EE);
  // contiguous zero-region: agg | cntdst | cntsrc (memset BEFORE k_prep)
  char* z0 = p;
  float* agg           = (float*)carve(sizeof(float) * NS * DD);
  int* cntdst          = (int*)carve(sizeof(int) * NS);
  int* cntsrc          = (int*)carve(sizeof(int) * NS);
  size_t zlen = (size_t)(p - z0);
  size_t fixed = (size_t)(p - (char*)d_ws);

  size_t freeb = (ws_size > fixed) ? (ws_size - fixed - 256) : 0;
  int rows = (int)(freeb / (sizeof(short) * HH * DD));
  if (rows >= NS) rows = NS;       // single chunk when it fits (ws = 256 MiB)
  else { rows &= ~63; if (rows < 64) rows = 64; }
  unsigned short* Tt = (unsigned short*)carve(sizeof(short) * (size_t)rows * HH * DD);

  hipMemsetAsync(z0, 0, zlen, stream);
  k_prep<<<dim3(TBLK + (NS + 3) / 4), dim3(256), 0, stream>>>(
      x, gamma, beta, h, hbf, ea, eabf, w2, w2t2, w1, w1t, b2, b2t,
      ei, cntsrc, cntdst);

  bool first = true;
  for (int n0 = 0; n0 < NS; n0 += rows) {
    int n1 = n0 + rows;
    if (n1 > NS) n1 = NS;
    int nr = n1 - n0;
    int gx = (((nr + 63) / 64) + 7) & ~7;   // mult of 8 for XCD pinning
    k_midT<<<dim3(TSTART + gx * (HH * DD / 128)), dim3(256), 0, stream>>>(
        eabf, w1t, b1, ubf, hbf, b2t, cc, cntsrc, rowptr, cursor,
        w2t2, Tt, n0, n1, gx, first ? 1 : 0);
    if (first)
      k_scatter<<<dim3((EE + 255) / 256), dim3(256), 0, stream>>>(ei, cursor, eord);
    k_msg_wave<<<dim3(gx, 16), dim3(256), 0, stream>>>(
        ubf, Tt, cc, ei, rowptr, eord, agg, n0, n1);
    first = false;
  }

  k_final<<<dim3((NS + 31) / 32), dim3(256), 0, stream>>>(x, h, root, bias, agg,
                                                          cntdst, out);
}